// Round 1
// baseline (752.898 us; speedup 1.0000x reference)
//
#include <hip/hip_runtime.h>
#include <math.h>

#define HW    (512 * 512)
#define FCH   64
#define NB    8
#define NID   32
#define CHUNK 4096
#define ACC_STRIDE 33   // 33 % 32 == 1 -> bank = (f + id-1) % 32, conflict-spread

// ---------------------------------------------------------------------------
// Kernel 1: per-instance segment max over encoded [B, F, H, W], ids in masks.
// Block = (chunk, batch). Stage ids in LDS once; each wave owns 16 channels,
// reads float4-coalesced feature rows, LDS-atomicMax (uint trick, v>=0) into
// a per-wave [64][33] accumulator; merge waves and global-atomicMax out.
// ---------------------------------------------------------------------------
__global__ __launch_bounds__(256) void segmax_kernel(
    const float* __restrict__ encoded,
    const int*   __restrict__ masks,
    float*       __restrict__ vectors)   // [B, NID, F], pre-zeroed
{
    const int b      = blockIdx.y;
    const int chunk0 = blockIdx.x * CHUNK;
    const int tid    = threadIdx.x;
    const int wave   = tid >> 6;
    const int lane   = tid & 63;

    __shared__ int   ids[CHUNK];                    // 16 KB
    __shared__ float acc[4][FCH * ACC_STRIDE];      // 4 waves * 2112 f = 33 KB

    // zero accumulators
    for (int i = tid; i < 4 * FCH * ACC_STRIDE; i += 256)
        ((float*)acc)[i] = 0.0f;

    // stage ids for this chunk (read once per block, not once per channel)
    {
        const int4* msrc = (const int4*)(masks + (size_t)b * HW + chunk0);
        int4* mdst = (int4*)ids;
        for (int i = tid; i < CHUNK / 4; i += 256)
            mdst[i] = msrc[i];
    }
    __syncthreads();

    const float* ebase = encoded + (size_t)b * FCH * HW + chunk0;
    float* wacc = acc[wave];

    for (int k = 0; k < 16; ++k) {
        const int f = wave * 16 + k;
        const float4* src = (const float4*)(ebase + (size_t)f * HW);
        float* facc = wacc + f * ACC_STRIDE;
#pragma unroll 4
        for (int it = 0; it < CHUNK / 256; ++it) {  // 16 iters of float4
            const int idx = it * 64 + lane;
            float4 v  = src[idx];
            int4   id = ((const int4*)ids)[idx];
            if (id.x > 0 && v.x > 0.0f) atomicMax((unsigned*)&facc[id.x - 1], __float_as_uint(v.x));
            if (id.y > 0 && v.y > 0.0f) atomicMax((unsigned*)&facc[id.y - 1], __float_as_uint(v.y));
            if (id.z > 0 && v.z > 0.0f) atomicMax((unsigned*)&facc[id.z - 1], __float_as_uint(v.z));
            if (id.w > 0 && v.w > 0.0f) atomicMax((unsigned*)&facc[id.w - 1], __float_as_uint(v.w));
        }
    }
    __syncthreads();

    // merge the 4 per-wave copies, one global atomic per (id, f)
    for (int e = tid; e < FCH * NID; e += 256) {
        const int f = e >> 5;   // 0..63
        const int n = e & 31;   // id-1
        float m = acc[0][f * ACC_STRIDE + n];
        m = fmaxf(m, acc[1][f * ACC_STRIDE + n]);
        m = fmaxf(m, acc[2][f * ACC_STRIDE + n]);
        m = fmaxf(m, acc[3][f * ACC_STRIDE + n]);
        if (m > 0.0f)
            atomicMax((unsigned*)&vectors[((size_t)b * NID + n) * FCH + f],
                      __float_as_uint(m));
    }
}

// ---------------------------------------------------------------------------
// Kernel 2: collapsed pairwise MLP.
// out[b,i,j,c] = sigmoid(v_i·A[:,c] + v_j·B[:,c] + cc[c]),
// A = w1[:64]@w2, B = w1[64:]@w2, cc = b1@w2 + b2.
// connections[b, c, j, i] = out[b, i, j, c].
// ---------------------------------------------------------------------------
__global__ __launch_bounds__(256) void conn_kernel(
    const float* __restrict__ vectors,  // [B, NID, F]
    const float* __restrict__ w1,       // [128, 32]
    const float* __restrict__ b1,       // [32]
    const float* __restrict__ w2,       // [32, 4]
    const float* __restrict__ b2,       // [4]
    float*       __restrict__ out)      // [B, 4, NID, NID]
{
    const int b   = blockIdx.x;
    const int tid = threadIdx.x;

    __shared__ float v[NID][FCH];
    __shared__ float A[FCH][4], Bm[FCH][4];
    __shared__ float s[NID][4], t[NID][4];
    __shared__ float cc[4];

    for (int i = tid; i < NID * FCH; i += 256)
        ((float*)v)[i] = vectors[(size_t)b * NID * FCH + i];

    {
        const int k = tid >> 2, c = tid & 3;
        float a = 0.0f, bb = 0.0f;
#pragma unroll
        for (int h = 0; h < 32; ++h) {
            const float w2v = w2[h * 4 + c];
            a  += w1[k * 32 + h]        * w2v;
            bb += w1[(k + 64) * 32 + h] * w2v;
        }
        A[k][c]  = a;
        Bm[k][c] = bb;
        if (tid < 4) {
            float x = b2[tid];
#pragma unroll
            for (int h = 0; h < 32; ++h) x += b1[h] * w2[h * 4 + tid];
            cc[tid] = x;
        }
    }
    __syncthreads();

    if (tid < 128) {
        const int i = tid >> 2, c = tid & 3;
        float a = 0.0f;
#pragma unroll
        for (int f = 0; f < FCH; ++f) a += v[i][f] * A[f][c];
        s[i][c] = a;
    } else {
        const int j = (tid - 128) >> 2, c = tid & 3;
        float a = 0.0f;
#pragma unroll
        for (int f = 0; f < FCH; ++f) a += v[j][f] * Bm[f][c];
        t[j][c] = a;
    }
    __syncthreads();

    for (int o = tid; o < 4 * NID * NID; o += 256) {
        const int i = o & 31;
        const int j = (o >> 5) & 31;
        const int c = o >> 10;
        const float x = s[i][c] + t[j][c] + cc[c];
        out[(((size_t)b * 4 + c) * NID + j) * NID + i] = 1.0f / (1.0f + expf(-x));
    }
}

extern "C" void kernel_launch(void* const* d_in, const int* in_sizes, int n_in,
                              void* d_out, int out_size, void* d_ws, size_t ws_size,
                              hipStream_t stream) {
    const float* encoded = (const float*)d_in[0];
    const int*   masks   = (const int*)d_in[1];
    const float* w1      = (const float*)d_in[2];
    const float* b1      = (const float*)d_in[3];
    const float* w2      = (const float*)d_in[4];
    const float* b2      = (const float*)d_in[5];
    float* out = (float*)d_out;

    float* vectors     = out;                        // NB*NID*FCH = 16384 floats
    float* connections = out + NB * NID * FCH;       // NB*4*NID*NID = 32768 floats

    // vectors must start at 0 (atomicMax accumulation; absent id -> 0)
    hipMemsetAsync(vectors, 0, (size_t)NB * NID * FCH * sizeof(float), stream);

    segmax_kernel<<<dim3(HW / CHUNK, NB), 256, 0, stream>>>(encoded, masks, vectors);
    conn_kernel<<<NB, 256, 0, stream>>>(vectors, w1, b1, w2, b2, connections);
}

// Round 2
// 714.428 us; speedup vs baseline: 1.0538x; 1.0538x over previous
//
#include <hip/hip_runtime.h>
#include <math.h>

#define HW    (512 * 512)
#define FCH   64
#define NB    8
#define NID   32
#define CHUNK 4096
#define ACC_STRIDE 33   // bank = (f + id-1) % 32 -> distinct ids hit distinct banks

// ---------------------------------------------------------------------------
// Kernel 1: per-instance segment max over encoded [B, F, H, W], ids in masks.
// Block = (4096-pixel chunk, batch), 512 threads (8 waves). Stage ids in LDS
// once; ONE shared [64][33] accumulator (cross-wave LDS atomics serialize in
// the pipe anyway — private copies only cost LDS/occupancy). Each wave owns 8
// channels, float4-coalesced reads, ds_max_u32 via the non-negative-float
// uint-monotone trick. Finalize with one global atomicMax per (id, f).
// ---------------------------------------------------------------------------
__global__ __launch_bounds__(512) void segmax_kernel(
    const float* __restrict__ encoded,
    const int*   __restrict__ masks,
    float*       __restrict__ vectors)   // [B, NID, F], pre-zeroed
{
    const int b      = blockIdx.y;
    const int chunk0 = blockIdx.x * CHUNK;
    const int tid    = threadIdx.x;
    const int wave   = tid >> 6;
    const int lane   = tid & 63;

    __shared__ int   ids[CHUNK];              // 16 KB
    __shared__ float acc[FCH * ACC_STRIDE];   // 8.25 KB

    for (int i = tid; i < FCH * ACC_STRIDE; i += 512)
        acc[i] = 0.0f;

    {
        const int4* msrc = (const int4*)(masks + (size_t)b * HW + chunk0);
        int4* mdst = (int4*)ids;
        for (int i = tid; i < CHUNK / 4; i += 512)
            mdst[i] = msrc[i];
    }
    __syncthreads();

    const float* ebase = encoded + (size_t)b * FCH * HW + chunk0;

    for (int k = 0; k < 8; ++k) {
        const int f = wave * 8 + k;
        const float4* src = (const float4*)(ebase + (size_t)f * HW);
        float* facc = acc + f * ACC_STRIDE;
#pragma unroll 4
        for (int it = 0; it < 16; ++it) {   // 16 x float4 per lane per channel
            const int idx = it * 64 + lane;
            float4 v  = src[idx];
            int4   id = ((const int4*)ids)[idx];
            if (id.x > 0 && v.x > 0.0f) atomicMax((unsigned*)&facc[id.x - 1], __float_as_uint(v.x));
            if (id.y > 0 && v.y > 0.0f) atomicMax((unsigned*)&facc[id.y - 1], __float_as_uint(v.y));
            if (id.z > 0 && v.z > 0.0f) atomicMax((unsigned*)&facc[id.z - 1], __float_as_uint(v.z));
            if (id.w > 0 && v.w > 0.0f) atomicMax((unsigned*)&facc[id.w - 1], __float_as_uint(v.w));
        }
    }
    __syncthreads();

    for (int e = tid; e < FCH * NID; e += 512) {
        const int f = e >> 5;   // 0..63
        const int n = e & 31;   // id-1
        const float m = acc[f * ACC_STRIDE + n];
        if (m > 0.0f)
            atomicMax((unsigned*)&vectors[((size_t)b * NID + n) * FCH + f],
                      __float_as_uint(m));
    }
}

// ---------------------------------------------------------------------------
// Kernel 2: collapsed pairwise MLP (no nonlinearity between layers):
// out[b,i,j,c] = sigmoid(v_i·A[:,c] + v_j·B[:,c] + cc[c]),
// A = w1[:64]@w2, B = w1[64:]@w2, cc = b1@w2 + b2.
// connections[b, c, j, i] = out[b, i, j, c].
// ---------------------------------------------------------------------------
__global__ __launch_bounds__(256) void conn_kernel(
    const float* __restrict__ vectors,  // [B, NID, F]
    const float* __restrict__ w1,       // [128, 32]
    const float* __restrict__ b1,       // [32]
    const float* __restrict__ w2,       // [32, 4]
    const float* __restrict__ b2,       // [4]
    float*       __restrict__ out)      // [B, 4, NID, NID]
{
    const int b   = blockIdx.x;
    const int tid = threadIdx.x;

    __shared__ float v[NID][FCH];
    __shared__ float A[FCH][4], Bm[FCH][4];
    __shared__ float s[NID][4], t[NID][4];
    __shared__ float cc[4];

    for (int i = tid; i < NID * FCH; i += 256)
        ((float*)v)[i] = vectors[(size_t)b * NID * FCH + i];

    {
        const int k = tid >> 2, c = tid & 3;
        float a = 0.0f, bb = 0.0f;
#pragma unroll
        for (int h = 0; h < 32; ++h) {
            const float w2v = w2[h * 4 + c];
            a  += w1[k * 32 + h]        * w2v;
            bb += w1[(k + 64) * 32 + h] * w2v;
        }
        A[k][c]  = a;
        Bm[k][c] = bb;
        if (tid < 4) {
            float x = b2[tid];
#pragma unroll
            for (int h = 0; h < 32; ++h) x += b1[h] * w2[h * 4 + tid];
            cc[tid] = x;
        }
    }
    __syncthreads();

    if (tid < 128) {
        const int i = tid >> 2, c = tid & 3;
        float a = 0.0f;
#pragma unroll
        for (int f = 0; f < FCH; ++f) a += v[i][f] * A[f][c];
        s[i][c] = a;
    } else {
        const int j = (tid - 128) >> 2, c = tid & 3;
        float a = 0.0f;
#pragma unroll
        for (int f = 0; f < FCH; ++f) a += v[j][f] * Bm[f][c];
        t[j][c] = a;
    }
    __syncthreads();

    for (int o = tid; o < 4 * NID * NID; o += 256) {
        const int i = o & 31;
        const int j = (o >> 5) & 31;
        const int c = o >> 10;
        const float x = s[i][c] + t[j][c] + cc[c];
        out[(((size_t)b * 4 + c) * NID + j) * NID + i] = 1.0f / (1.0f + expf(-x));
    }
}

extern "C" void kernel_launch(void* const* d_in, const int* in_sizes, int n_in,
                              void* d_out, int out_size, void* d_ws, size_t ws_size,
                              hipStream_t stream) {
    const float* encoded = (const float*)d_in[0];
    const int*   masks   = (const int*)d_in[1];
    const float* w1      = (const float*)d_in[2];
    const float* b1      = (const float*)d_in[3];
    const float* w2      = (const float*)d_in[4];
    const float* b2      = (const float*)d_in[5];
    float* out = (float*)d_out;

    float* vectors     = out;                        // NB*NID*FCH = 16384 floats
    float* connections = out + NB * NID * FCH;       // NB*4*NID*NID = 32768 floats

    // vectors must start at 0 (atomicMax accumulation; absent id -> 0)
    hipMemsetAsync(vectors, 0, (size_t)NB * NID * FCH * sizeof(float), stream);

    segmax_kernel<<<dim3(HW / CHUNK, NB), 512, 0, stream>>>(encoded, masks, vectors);
    conn_kernel<<<NB, 256, 0, stream>>>(vectors, w1, b1, w2, b2, connections);
}